// Round 11
// baseline (454.993 us; speedup 1.0000x reference)
//
#include <hip/hip_runtime.h>
#include <hip/hip_bf16.h>

// EPiC network, round 22: r19 restored (3-term, 413us verified) + two
// scheduling fixes. r21 post-mortem: 2-term emulation FAILED absmax
// (6.05e12 > 4.88e12) — reverted per pre-commitment.
// Fix 1: staging DMA issued AFTER the prologue tail (r19 issued it first, so
//   the tail's first __syncthreads vmcnt(0)-drained the whole 128KB DMA and
//   every tail load FIFO-waited behind it). Now: tail runs at own latency;
//   staging overlaps frag loads; one final barrier drains.
// Fix 2: cnt computed once (layer 0, verified path) -> cnt_g[b] scalar;
//   layers 1..5 load the scalar (1 barrier vs 64-load phase + 2 barriers).
// All math/layout/phase code verbatim r19.

typedef __attribute__((ext_vector_type(8))) short short8;
typedef __attribute__((ext_vector_type(4))) float f32x4;

#define B_ 16
#define N_ 8192
#define DC_ 16
#define H_ 128
#define G_ 10
#define NB_ 6
#define NEG_ 0.01f

__device__ __forceinline__ float lrelu(float x) { return x > 0.f ? x : NEG_ * x; }

__device__ __forceinline__ unsigned short f2bf(float x) {
  union { float f; unsigned u; } v; v.f = x;
  return (unsigned short)((v.u + 0x7fffu + ((v.u >> 16) & 1u)) >> 16);  // RNE
}
__device__ __forceinline__ float bf2f(unsigned short u) {
  union { unsigned u; float f; } v; v.u = ((unsigned)u) << 16; return v.f;
}
// truncating hi (1 op) + RNE lo of residual; pair represents x to ~2^-17
__device__ __forceinline__ void split_bf(float x, unsigned short& h, unsigned short& l) {
  union { float f; unsigned u; } v; v.f = x;
  unsigned hu = v.u & 0xffff0000u;
  h = (unsigned short)(hu >> 16);
  union { unsigned u; float f; } hv; hv.u = hu;
  l = f2bf(x - hv.f);
}

__device__ __forceinline__ f32x4 mfma16(short8 a, short8 b, f32x4 c) {
  return __builtin_amdgcn_mfma_f32_16x16x32_bf16(a, b, c, 0, 0, 0);
}

__device__ __forceinline__ void make_frags(f32x4 v0, f32x4 v1, short8& bh, short8& bl) {
  unsigned short h, l;
#pragma unroll
  for (int j = 0; j < 4; ++j) {
    split_bf(v0[j], h, l);
    bh[j] = (short)h; bl[j] = (short)l;
  }
#pragma unroll
  for (int j = 0; j < 4; ++j) {
    split_bf(v1[j], h, l);
    bh[4 + j] = (short)h; bl[4 + j] = (short)l;
  }
}

// async 16B-per-lane global -> LDS copy (lane-contiguous DMA)
__device__ __forceinline__ void async_cp16(const void* g, void* l) {
  __builtin_amdgcn_global_load_lds(
      (const __attribute__((address_space(1))) void*)g,
      (__attribute__((address_space(3))) void*)l, 16, 0, 0);
}

// agent-scope write-through publication (no L2 flush)
__device__ __forceinline__ void agent_store(float* p, float v) {
  __hip_atomic_store(p, v, __ATOMIC_RELAXED, __HIP_MEMORY_SCOPE_AGENT);
}
__device__ __forceinline__ float agent_load(const float* p) {
  return __hip_atomic_load(p, __ATOMIC_RELAXED, __HIP_MEMORY_SCOPE_AGENT);
}

// ---- common tail: pool(NS slots) -> h_g -> xg residual -> folded gbias ----
// blockDim-agnostic: compute guarded, barriers unconditional. (verified r19)
template <int NS>
__device__ void epic_global_tail(
    int b, int tid, const float* __restrict__ pP, float cnt,
    const float* __restrict__ xg_cur, float* __restrict__ xg_next,
    const float* __restrict__ context,
    const float* __restrict__ g1w_n, const float* __restrict__ g1b_n,
    const float* __restrict__ g2w_n, const float* __restrict__ g2b_n,
    const float* __restrict__ l1w_n, const float* __restrict__ l1b_n,
    float* __restrict__ gbias_out, float* shx) {
  if (tid < 256) {
    const int f = tid & 127, kh = tid >> 7;
    const float* pr = pP + ((size_t)b * NS + kh * (NS / 2)) * 128 + f;
    float s = 0.f;
#pragma unroll 8
    for (int w = 0; w < NS / 2; ++w) s += agent_load(pr + w * 128);
    shx[tid] = s;
  }
  __syncthreads();
  if (tid < 128) {
    float s = shx[tid] + shx[tid + 128];
    shx[384 + tid] = s;
    shx[256 + tid] = s / cnt;
  }
  if (tid < G_) shx[512 + tid] = xg_cur[tid];
  if (tid >= 32 && tid < 32 + DC_) shx[522 + tid - 32] = context[b * DC_ + tid - 32];
  __syncthreads();
  if (tid < 256) {
    const int f = tid & 127, kh = tid >> 7;
    const float* wr = g1w_n + (size_t)f * 282 + kh * 142;
    const float* vp = shx + 256 + kh * 142;
    const int n2 = kh ? 70 : 71;
    float a = 0.f;
#pragma unroll 8
    for (int j = 0; j < n2; ++j) {
      float2 w2 = *(const float2*)(wr + 2 * j);
      a += w2.x * vp[2 * j] + w2.y * vp[2 * j + 1];
    }
    shx[tid] = a;  // writes 0..255; reads were 256..539 (disjoint)
  }
  __syncthreads();
  if (tid < 128) shx[544 + tid] = lrelu(shx[tid] + shx[tid + 128] + g1b_n[tid]);
  __syncthreads();
  if (tid < G_) {
    const float* wr = g2w_n + tid * 128;
    float a = g2b_n[tid] + shx[512 + tid];
#pragma unroll 8
    for (int j = 0; j < 32; ++j) {
      float4 w4 = *(const float4*)(wr + 4 * j);
      a += w4.x * shx[544 + 4 * j] + w4.y * shx[544 + 4 * j + 1] +
           w4.z * shx[544 + 4 * j + 2] + w4.w * shx[544 + 4 * j + 3];
    }
    float v = lrelu(a);
    shx[672 + tid] = v;
    xg_next[tid] = v;
  }
  __syncthreads();
  if (tid < 128) {
    const float* wr = l1w_n + tid * 154;
    float a = l1b_n[tid];
#pragma unroll
    for (int j = 0; j < G_; ++j) a += wr[128 + j] * shx[672 + j];
#pragma unroll
    for (int j = 0; j < DC_; ++j) a += wr[138 + j] * shx[522 + j];
    gbias_out[tid] = a;
  }
  __syncthreads();
}

// ---- shared prologue: (FIRST: proj MLP -> xg_0) + this-layer tail ----
// cnt supplied by caller. gbias lands in LDS. (verified r19 phase code)
template <bool FIRST, int NS>
__device__ void epic_prologue(
    int b, int tid, int layer, float cnt,
    const float* __restrict__ pP_in,
    const float* __restrict__ context, float* __restrict__ xg_g,
    const float* __restrict__ g1w_i, const float* __restrict__ g1b_i,
    const float* __restrict__ g2w_i, const float* __restrict__ g2b_i,
    const float* __restrict__ l1w_i, const float* __restrict__ l1b_i,
    const float* __restrict__ g0w, const float* __restrict__ g0b,
    const float* __restrict__ g1pw, const float* __restrict__ g1pb,
    const float* __restrict__ g2pw, const float* __restrict__ g2pb,
    float* gbias_s, float* shx) {
  if (FIRST) {
    // ---- proj global MLP: pool(128) -> g0 -> g1p -> g2p -> xg_0 ----
    if (tid < 256) {
      const int f = tid & 127, kh = tid >> 7;
      const float* pr = pP_in + ((size_t)b * 128 + kh * 64) * 128 + f;
      float s = 0.f;
#pragma unroll 8
      for (int w = 0; w < 64; ++w) s += agent_load(pr + w * 128);
      shx[tid] = s;
    }
    __syncthreads();
    if (tid < 128) {
      float s = shx[tid] + shx[tid + 128];
      shx[384 + tid] = s;
      shx[256 + tid] = s / cnt;
    }
    if (tid < DC_) shx[512 + tid] = context[b * DC_ + tid];
    __syncthreads();
    {
      float a = 0.f;
      if (tid < 256) {
        const int f = tid & 127, kh = tid >> 7;
        const float* wr = g0w + (size_t)f * 272 + kh * 136;
        const float* vp = shx + 256 + kh * 136;
#pragma unroll 8
        for (int j = 0; j < 34; ++j) {
          float4 w4 = *(const float4*)(wr + 4 * j);
          a += w4.x * vp[4 * j] + w4.y * vp[4 * j + 1] + w4.z * vp[4 * j + 2] + w4.w * vp[4 * j + 3];
        }
      }
      __syncthreads();
      if (tid < 256) shx[tid] = a;
    }
    __syncthreads();
    if (tid < 128) shx[544 + tid] = lrelu(shx[tid] + shx[tid + 128] + g0b[tid]);
    __syncthreads();
    {
      float a = 0.f;
      if (tid < 256) {
        const int f = tid & 127, kh = tid >> 7;
        const float* wr = g1pw + (size_t)f * 128 + kh * 64;
        const float* vp = shx + 544 + kh * 64;
#pragma unroll 8
        for (int j = 0; j < 16; ++j) {
          float4 w4 = *(const float4*)(wr + 4 * j);
          a += w4.x * vp[4 * j] + w4.y * vp[4 * j + 1] + w4.z * vp[4 * j + 2] + w4.w * vp[4 * j + 3];
        }
      }
      __syncthreads();
      if (tid < 256) shx[tid] = a;
    }
    __syncthreads();
    if (tid < 128) shx[544 + tid] = lrelu(shx[tid] + shx[tid + 128] + g1pb[tid]);
    __syncthreads();
    if (tid < G_) {
      const float* wr = g2pw + tid * 128;
      float a = g2pb[tid];
#pragma unroll 8
      for (int j = 0; j < 32; ++j) {
        float4 w4 = *(const float4*)(wr + 4 * j);
        a += w4.x * shx[544 + 4 * j] + w4.y * shx[544 + 4 * j + 1] +
             w4.z * shx[544 + 4 * j + 2] + w4.w * shx[544 + 4 * j + 3];
      }
      xg_g[(0 * 16 + b) * 16 + tid] = lrelu(a);  // identical across batch WGs
    }
    __syncthreads();
  }
  // ---- this layer's tail: gbias_i -> LDS, xg_{i+1} -> global slot ----
  epic_global_tail<NS>(b, tid, pP_in, cnt,
                       xg_g + ((size_t)layer * 16 + b) * 16,
                       xg_g + ((size_t)(layer + 1) * 16 + b) * 16, context,
                       g1w_i, g1b_i, g2w_i, g2b_i, l1w_i, l1b_i, gbias_s, shx);
}

// ---------------- weight prep: split + frag-order swizzle (3-term) ----------
__global__ __launch_bounds__(256) void prep_weights(
    const float* __restrict__ l1w, const float* __restrict__ l2w,
    unsigned short* __restrict__ w1h, unsigned short* __restrict__ w1l,
    unsigned short* __restrict__ w2h, unsigned short* __restrict__ w2l) {
  int idx = blockIdx.x * 256 + threadIdx.x;
  const int total = NB_ * H_ * H_;
  if (idx < total) {
    int i = idx / (H_ * H_), rem = idx % (H_ * H_);
    int F = rem / H_, k = rem % H_;
    int ks = k >> 5, c = k & 31;
    int mt2 = F >> 4, r2 = F & 15;
    int mt1 = ((F >> 5) << 1) | ((F >> 2) & 1);
    int r1 = (((F >> 3) & 3) << 2) | (F & 3);
    int off1 = i * 16384 + (mt1 * 4 + ks) * 512 + ((c >> 3) * 16 + r1) * 8 + (c & 7);
    int off2 = i * 16384 + (mt2 * 4 + ks) * 512 + ((c >> 3) * 16 + r2) * 8 + (c & 7);
    unsigned short h, l;
    split_bf(l1w[(i * H_ + F) * 154 + k], h, l);
    w1h[off1] = h; w1l[off1] = l;
    split_bf(l2w[(i * H_ + F) * H_ + k], h, l);
    w2h[off2] = h; w2l[off2] = l;
  }
}

// ---------------- projection local (pure local: xlf + pP + cntp) ----------
__global__ __launch_bounds__(256, 2) void proj_local_kernel(
    const float* __restrict__ xloc, const float* __restrict__ maskp,
    const float* __restrict__ plw, const float* __restrict__ plb,
    float* __restrict__ xlf, float* __restrict__ pP,
    float* __restrict__ cntp) {
  __shared__ float wq[H_][4];
  __shared__ float wsum[512];
  __shared__ float cw[4];
  const int tid = threadIdx.x, bid = blockIdx.x;
  const int wv = tid >> 6, lane = tid & 63;
  const int q = lane >> 4, n16 = lane & 15;
  if (tid < H_) {
    wq[tid][0] = plw[tid * 3 + 0];
    wq[tid][1] = plw[tid * 3 + 1];
    wq[tid][2] = plw[tid * 3 + 2];
    wq[tid][3] = plb[tid];
  }
  __syncthreads();
  const int t = bid * 4 + wv;            // 32-pt tile index
  const int p0 = t * 32;
  const int pa = p0 + n16, pb = p0 + 16 + n16;
  const float xa0 = xloc[pa * 3], xa1 = xloc[pa * 3 + 1], xa2 = xloc[pa * 3 + 2];
  const float xb0 = xloc[pb * 3], xb1 = xloc[pb * 3 + 1], xb2 = xloc[pb * 3 + 2];
  const float m0 = maskp[pa], m1 = maskp[pb];
  float* ga = xlf + (size_t)(2 * t) * 2048;
  float* gb = ga + 2048;
#pragma unroll
  for (int ms = 0; ms < 8; ++ms) {
    f32x4 v0, v1;
#pragma unroll
    for (int r = 0; r < 4; ++r) {
      const int F = ms * 16 + q * 4 + r;
      float4 w4 = *(const float4*)wq[F];
      v0[r] = lrelu(w4.x * xa0 + w4.y * xa1 + w4.z * xa2 + w4.w) * m0;
      v1[r] = lrelu(w4.x * xb0 + w4.y * xb1 + w4.z * xb2 + w4.w) * m1;
    }
    *(f32x4*)(ga + ms * 256 + (q * 16 + n16) * 4) = v0;
    *(f32x4*)(gb + ms * 256 + (q * 16 + n16) * 4) = v1;
    f32x4 s = v0 + v1;
#pragma unroll
    for (int r = 0; r < 4; ++r) {
      float sv = s[r];
      sv += __shfl_xor(sv, 1, 64);
      sv += __shfl_xor(sv, 2, 64);
      sv += __shfl_xor(sv, 4, 64);
      sv += __shfl_xor(sv, 8, 64);
      s[r] = sv;
    }
    if (n16 == 0) *(f32x4*)&wsum[wv * 128 + ms * 16 + q * 4] = s;
  }
  {
    float c = (q == 0) ? (m0 + m1) : 0.f;
    c += __shfl_xor(c, 1, 64);
    c += __shfl_xor(c, 2, 64);
    c += __shfl_xor(c, 4, 64);
    c += __shfl_xor(c, 8, 64);
    if (lane == 0) cw[wv] = c;
  }
  __syncthreads();
  // two 64-pt slots per WG -> 128 slots per batch
  if (tid < 128) {
    agent_store(&pP[(size_t)(2 * bid) * 128 + tid], wsum[tid] + wsum[128 + tid]);
    agent_store(&pP[(size_t)(2 * bid + 1) * 128 + tid], wsum[256 + tid] + wsum[384 + tid]);
  }
  if (tid == 0) agent_store(&cntp[bid], cw[0] + cw[1] + cw[2] + cw[3]);
}

// ---- per-group x B-frag load (B-layout, verified) ----
__device__ __forceinline__ void load_frags(const float* base_g, int q, int n16,
                                           short8* xbh, short8* xbl) {
#pragma unroll
  for (int ks = 0; ks < 4; ++ks) {
    const float* pb = base_g + (2 * ks + (q >> 1)) * 256 + ((q & 1) * 32 + n16) * 4;
    f32x4 v0 = *(const f32x4*)pb;
    f32x4 v1 = *(const f32x4*)(pb + 64);
    make_frags(v0, v1, xbh[ks], xbl[ks]);
  }
}

// ---- one group's K-loop + epilogue, 3-TERM (verified r16/r18/r19) ----
template <bool LAST>
__device__ __forceinline__ void epic_pass(
    int g, int wv, int q, int n16, int lane16,
    const short8* xbh, const short8* xbl,
    const unsigned short* w1h_l, const unsigned short* w1l_l,
    const unsigned short* w2h_l, const unsigned short* w2l_l,
    const float* gbias_s, const float* l2b_s, const float* outw_s,
    float* wsum, float* __restrict__ xlf, const float* __restrict__ maskp,
    float* __restrict__ outp) {
  f32x4 acc2[8];
#pragma unroll
  for (int ms = 0; ms < 8; ++ms) acc2[ms] = (f32x4){0.f, 0.f, 0.f, 0.f};

#pragma unroll 1
  for (int ko = 0; ko < 4; ++ko) {
    f32x4 acc[2][2];
#pragma unroll
    for (int t = 0; t < 2; ++t)
#pragma unroll
      for (int kc = 0; kc < 2; ++kc) acc[t][kc] = (f32x4){0.f, 0.f, 0.f, 0.f};
#pragma unroll
    for (int t = 0; t < 2; ++t) {
#pragma unroll
      for (int kc = 0; kc < 2; ++kc) {  // ks chunks of 2 (16 transient regs)
        short8 a1h[2], a1l[2];
#pragma unroll
        for (int u = 0; u < 2; ++u) {
          const int off = ((ko * 2 + t) * 4 + kc * 2 + u) * 512 + lane16;
          a1h[u] = *(const short8*)(w1h_l + off);
          a1l[u] = *(const short8*)(w1l_l + off);
        }
#pragma unroll
        for (int u = 0; u < 2; ++u) {
          const int ks = kc * 2 + u;
          acc[t][kc] = mfma16(a1h[u], xbh[ks], acc[t][kc]);
          acc[t][kc] = mfma16(a1l[u], xbh[ks], acc[t][kc]);
          acc[t][kc] = mfma16(a1h[u], xbl[ks], acc[t][kc]);
        }
      }
    }
    f32x4 gb0 = *(const f32x4*)&gbias_s[ko * 32 + q * 8];
    f32x4 gb1 = *(const f32x4*)&gbias_s[ko * 32 + q * 8 + 4];
    f32x4 hv0, hv1;
#pragma unroll
    for (int r = 0; r < 4; ++r) {
      hv0[r] = lrelu(acc[0][0][r] + acc[0][1][r] + gb0[r]);
      hv1[r] = lrelu(acc[1][0][r] + acc[1][1][r] + gb1[r]);
    }
    short8 b2h, b2l;
    make_frags(hv0, hv1, b2h, b2l);
#pragma unroll
    for (int mc = 0; mc < 4; ++mc) {
      short8 a2h[2], a2l[2];
#pragma unroll
      for (int u = 0; u < 2; ++u) {
        const int off = ((mc * 2 + u) * 4 + ko) * 512 + lane16;
        a2h[u] = *(const short8*)(w2h_l + off);
        a2l[u] = *(const short8*)(w2l_l + off);
      }
#pragma unroll
      for (int u = 0; u < 2; ++u) {
        const int ms = mc * 2 + u;
        acc2[ms] = mfma16(a2h[u], b2h, acc2[ms]);
        acc2[ms] = mfma16(a2l[u], b2h, acc2[ms]);
        acc2[ms] = mfma16(a2h[u], b2l, acc2[ms]);
      }
    }
  }

  const float mk = maskp[g * 16 + n16];
  float po[3];
  if (LAST) po[0] = po[1] = po[2] = 0.f;
  float* base_w = xlf + (size_t)g * 2048;
#pragma unroll
  for (int ms = 0; ms < 8; ++ms) {
    f32x4 lb4 = *(const f32x4*)&l2b_s[ms * 16 + q * 4];
    float* xo = base_w + ms * 256 + (q * 16 + n16) * 4;
    f32x4 old = *(const f32x4*)xo;
    f32x4 v;
#pragma unroll
    for (int r = 0; r < 4; ++r) v[r] = lrelu(acc2[ms][r] + lb4[r] + old[r]) * mk;
    if (!LAST) {
      *(f32x4*)xo = v;
      f32x4 sr;
#pragma unroll
      for (int r = 0; r < 4; ++r) {
        float s = v[r];
        s += __shfl_xor(s, 1, 64);
        s += __shfl_xor(s, 2, 64);
        s += __shfl_xor(s, 4, 64);
        s += __shfl_xor(s, 8, 64);
        sr[r] = s;
      }
      if (n16 == 0) *(f32x4*)&wsum[wv * 128 + ms * 16 + q * 4] = sr;
    } else {
      f32x4 w0 = *(const f32x4*)&outw_s[0 * 128 + ms * 16 + q * 4];
      f32x4 w1 = *(const f32x4*)&outw_s[1 * 128 + ms * 16 + q * 4];
      f32x4 w2 = *(const f32x4*)&outw_s[2 * 128 + ms * 16 + q * 4];
#pragma unroll
      for (int r = 0; r < 4; ++r) {
        po[0] += v[r] * w0[r];
        po[1] += v[r] * w1[r];
        po[2] += v[r] * w2[r];
      }
    }
  }
  if (LAST) {
#pragma unroll
    for (int o = 0; o < 3; ++o) {
      float s = po[o];
      s += __shfl_xor(s, 16, 64);
      s += __shfl_xor(s, 32, 64);
      po[o] = s;
    }
    if (q == 0) {
      const int p = g * 16 + n16;
#pragma unroll
      for (int o = 0; o < 3; ++o)
        outp[(size_t)p * 3 + o] = (po[o] + outw_s[384 + o]) * mk;
    }
  }
}

// ---------------- epic local (layers 0..4): tail -> staging -> 2 passes ------
template <bool FIRST>
__global__ __launch_bounds__(1024) void epic_local_kernel(
    float* __restrict__ xlf,
    const float* __restrict__ pP_in, float* __restrict__ pP_out,
    const float* __restrict__ cntp, float* __restrict__ cnt_g,
    const float* __restrict__ context,
    float* __restrict__ xg_g, int layer,
    const float* __restrict__ g1w_i, const float* __restrict__ g1b_i,
    const float* __restrict__ g2w_i, const float* __restrict__ g2b_i,
    const float* __restrict__ l1w_i, const float* __restrict__ l1b_i,
    const float* __restrict__ g0w, const float* __restrict__ g0b,
    const float* __restrict__ g1pw, const float* __restrict__ g1pb,
    const float* __restrict__ g2pw, const float* __restrict__ g2pb,
    const float* __restrict__ l2b,
    const unsigned short* __restrict__ w1h, const unsigned short* __restrict__ w1l,
    const unsigned short* __restrict__ w2h, const unsigned short* __restrict__ w2l,
    const float* __restrict__ maskp) {
  __shared__ unsigned short wbuf[65536];  // 128 KB: w1h|w1l|w2h|w2l
  __shared__ float shx[768];
  __shared__ float gbias_s[128];
  __shared__ float l2b_s[128];
  __shared__ float wsum[2048];
  const int tid = threadIdx.x, bid = blockIdx.x;
  const int b = bid >> 4;   // 16 WGs per batch
  const int wv = tid >> 6, lane = tid & 63;
  const int q = lane >> 4, n16 = lane & 15;

  if (tid < 128) l2b_s[tid] = l2b[tid];

  // ---- cnt: layer 0 computes + publishes; others load the scalar ----
  if (FIRST) {
    if (tid < 64) shx[688 + tid] = agent_load(&cntp[b * 64 + tid]);
    __syncthreads();
    if (tid == 0) {
      float c = 0.f;
#pragma unroll
      for (int w = 0; w < 64; ++w) c += shx[688 + w];
      shx[752] = c;
      agent_store(&cnt_g[b], c);
    }
    __syncthreads();
  } else {
    if (tid == 0) shx[752] = agent_load(&cnt_g[b]);
    __syncthreads();
  }
  const float cnt = shx[752];

  // ---- prologue tail FIRST (no staging in flight -> no vmcnt drain stalls) ----
  epic_prologue<FIRST, FIRST ? 128 : 32>(
      b, tid, layer, cnt, pP_in, context, xg_g,
      g1w_i, g1b_i, g2w_i, g2b_i, l1w_i, l1b_i,
      g0w, g0b, g1pw, g1pb, g2pw, g2pb, gbias_s, shx);

  // ---- issue staging + overlap with pass-A frag loads ----
  {
    const unsigned short* src =
        (wv < 4) ? w1h : (wv < 8) ? w1l : (wv < 12) ? w2h : w2l;
    const char* s8 = (const char*)(src + (wv & 3) * 4096) + lane * 16;
    char* d8 = (char*)wbuf + wv * 8192;  // wave-uniform dest (lane*16 implicit)
#pragma unroll
    for (int j = 0; j < 8; ++j) async_cp16(s8 + j * 1024, d8 + j * 1024);
  }
  const int gA = bid * 32 + wv;
  const int gB = bid * 32 + 16 + wv;
  short8 xbh[4], xbl[4];
  load_frags(xlf + (size_t)gA * 2048, q, n16, xbh, xbl);
  __syncthreads();  // staging drained (vmcnt 0) + all waves ready

  const unsigned short* w1h_l = wbuf;
  const unsigned short* w1l_l = wbuf + 16384;
  const unsigned short* w2h_l = wbuf + 32768;
  const unsigned short* w2l_l = wbuf + 49152;
  const int lane16 = lane * 8;

  // ---- pass A ----
  epic_pass<false>(gA, wv, q, n16, lane16, xbh, xbl, w1h_l, w1l_l, w2h_l, w2l_l,
                   gbias_s, l2b_s, nullptr, wsum, xlf, maskp, nullptr);
  __syncthreads();
  if (tid < 128) {
    float s = 0.f;
#pragma unroll
    for (int w = 0; w < 16; ++w) s += wsum[w * 128 + tid];
    agent_store(&pP_out[(size_t)(bid * 2) * 128 + tid], s);
  }
  __syncthreads();  // protect wsum before pass B overwrites

  // ---- pass B ----
  load_frags(xlf + (size_t)gB * 2048, q, n16, xbh, xbl);
  epic_pass<false>(gB, wv, q, n16, lane16, xbh, xbl, w1h_l, w1l_l, w2h_l, w2l_l,
                   gbias_s, l2b_s, nullptr, wsum, xlf, maskp, nullptr);
  __syncthreads();
  if (tid < 128) {
    float s = 0.f;
#pragma unroll
    for (int w = 0; w < 16; ++w) s += wsum[w * 128 + tid];
    agent_store(&pP_out[(size_t)(bid * 2 + 1) * 128 + tid], s);
  }
}

// ---------------- LAST layer: tail -> staging -> head, 512 thr ----------------
__global__ __launch_bounds__(512, 2) void epic_last_kernel(
    const float* __restrict__ xlf,
    const float* __restrict__ pP_in, const float* __restrict__ cnt_g,
    const float* __restrict__ context, float* __restrict__ xg_g,
    const float* __restrict__ g1w_i, const float* __restrict__ g1b_i,
    const float* __restrict__ g2w_i, const float* __restrict__ g2b_i,
    const float* __restrict__ l1w_i, const float* __restrict__ l1b_i,
    const float* __restrict__ l2b,
    const unsigned short* __restrict__ w1h, const unsigned short* __restrict__ w1l,
    const unsigned short* __restrict__ w2h, const unsigned short* __restrict__ w2l,
    const float* __restrict__ maskp,
    const float* __restrict__ outw, const float* __restrict__ outb,
    float* __restrict__ outp) {
  __shared__ unsigned short wbuf[65536];  // 128 KB
  __shared__ float shx[768];
  __shared__ float gbias_s[128];
  __shared__ float l2b_s[128];
  __shared__ float outw_s[392];
  const int tid = threadIdx.x, bid = blockIdx.x;
  const int b = bid >> 4;
  const int wv = tid >> 6, lane = tid & 63;
  const int q = lane >> 4, n16 = lane & 15;
  const int lane16 = lane * 8;

  if (tid < 128) l2b_s[tid] = l2b[tid];
  if (tid < 384) outw_s[tid] = outw[tid];
  if (tid >= 384 && tid < 387) outw_s[tid] = outb[tid - 384];

  // ---- cnt from published scalar ----
  if (tid == 0) shx[752] = agent_load(&cnt_g[b]);
  __syncthreads();
  const float cnt = shx[752];

  // ---- prologue: layer-5 tail (gbias_5 -> LDS), no staging in flight ----
  epic_prologue<false, 32>(
      b, tid, 5, cnt, pP_in, context, xg_g,
      g1w_i, g1b_i, g2w_i, g2b_i, l1w_i, l1b_i,
      nullptr, nullptr, nullptr, nullptr, nullptr, nullptr, gbias_s, shx);

  // ---- issue staging + peel first frag load under it ----
  {
    const unsigned short* src =
        (wv < 2) ? w1h : (wv < 4) ? w1l : (wv < 6) ? w2h : w2l;
    const char* s8 = (const char*)(src + (wv & 1) * 8192) + lane * 16;
    char* d8 = (char*)wbuf + wv * 16384;
#pragma unroll
    for (int j = 0; j < 16; ++j) async_cp16(s8 + j * 1024, d8 + j * 1024);
  }
  const int g0 = bid * 32 + wv * 4;
  short8 xbh[4], xbl[4];
  load_frags(xlf + (size_t)g0 * 2048, q, n16, xbh, xbl);
  __syncthreads();  // staging drained

  const unsigned short* w1h_l = wbuf;
  const unsigned short* w1l_l = wbuf + 16384;
  const unsigned short* w2h_l = wbuf + 32768;
  const unsigned short* w2l_l = wbuf + 49152;

  epic_pass<true>(g0, wv, q, n16, lane16, xbh, xbl, w1h_l, w1l_l, w2h_l, w2l_l,
                  gbias_s, l2b_s, outw_s, gbias_s /*dead*/,
                  const_cast<float*>(xlf), maskp, outp);
#pragma unroll 1
  for (int p4 = 1; p4 < 4; ++p4) {
    const int g = g0 + p4;
    load_frags(xlf + (size_t)g * 2048, q, n16, xbh, xbl);
    epic_pass<true>(g, wv, q, n16, lane16, xbh, xbl, w1h_l, w1l_l, w2h_l, w2l_l,
                    gbias_s, l2b_s, outw_s, gbias_s /*dead*/,
                    const_cast<float*>(xlf), maskp, outp);
  }
}

extern "C" void kernel_launch(void* const* d_in, const int* in_sizes, int n_in,
                              void* d_out, int out_size, void* d_ws, size_t ws_size,
                              hipStream_t stream) {
  const float* x_local = (const float*)d_in[0];
  const float* context = (const float*)d_in[1];
  const float* mask = (const float*)d_in[2];
  const float* proj_lw = (const float*)d_in[3];
  const float* proj_lb = (const float*)d_in[4];
  const float* proj_g0w = (const float*)d_in[5];
  const float* proj_g0b = (const float*)d_in[6];
  const float* proj_g1w = (const float*)d_in[7];
  const float* proj_g1b = (const float*)d_in[8];
  const float* proj_g2w = (const float*)d_in[9];
  const float* proj_g2b = (const float*)d_in[10];
  const float* g1w = (const float*)d_in[11];
  const float* g1b = (const float*)d_in[12];
  const float* g2w = (const float*)d_in[13];
  const float* g2b = (const float*)d_in[14];
  const float* l1w = (const float*)d_in[15];
  const float* l1b = (const float*)d_in[16];
  const float* l2w = (const float*)d_in[17];
  const float* l2b = (const float*)d_in[18];
  const float* outw = (const float*)d_in[19];
  const float* outb = (const float*)d_in[20];
  float* out = (float*)d_out;

  char* ws = (char*)d_ws;
  float* xlf = (float*)ws;                                  // 67,108,864
  float* pP = (float*)(ws + 67108864);                      //  1,048,576 (proj, 128 slots/batch)
  float* cntp = (float*)(ws + 68157440);                    //      4,096
  float* cnt_g = (float*)(ws + 68161536);                   //         64
  float* xg_g = (float*)(ws + 68161600);                    //      7,168 (7 slots x 16 batches x 16)
  unsigned short* w1h = (unsigned short*)(ws + 68218368);   //    196,608
  unsigned short* w1l = (unsigned short*)(ws + 68414976);   //    196,608
  unsigned short* w2h = (unsigned short*)(ws + 68611584);   //    196,608
  unsigned short* w2l = (unsigned short*)(ws + 68808192);   //    196,608
  float* pPe0 = (float*)(ws + 69004800);                    //    262,144 (epic pool ping)
  float* pPe1 = (float*)(ws + 69266944);                    //    262,144 (epic pool pong)
  // end: 69,529,088 (< proven 70,018,304)

  prep_weights<<<384, 256, 0, stream>>>(l1w, l2w, w1h, w1l, w2h, w2l);
  proj_local_kernel<<<1024, 256, 0, stream>>>(
      x_local, mask, proj_lw, proj_lb, xlf, pP, cntp);
  for (int i = 0; i < NB_ - 1; ++i) {  // layers 0..4
    const float* pP_in = (i == 0) ? pP : ((i & 1) ? pPe1 : pPe0);
    float* pP_out = ((i + 1) & 1) ? pPe1 : pPe0;
    const float* g1w_i = g1w + (size_t)i * 128 * 282;
    const float* g1b_i = g1b + i * 128;
    const float* g2w_i = g2w + (size_t)i * 10 * 128;
    const float* g2b_i = g2b + i * 10;
    const float* l1w_i = l1w + (size_t)i * 128 * 154;
    const float* l1b_i = l1b + i * 128;
    const unsigned short* w1h_i = w1h + i * 16384;
    const unsigned short* w1l_i = w1l + i * 16384;
    const unsigned short* w2h_i = w2h + i * 16384;
    const unsigned short* w2l_i = w2l + i * 16384;
    if (i == 0) {
      epic_local_kernel<true><<<256, 1024, 0, stream>>>(
          xlf, pP_in, pP_out, cntp, cnt_g, context, xg_g, i,
          g1w_i, g1b_i, g2w_i, g2b_i, l1w_i, l1b_i,
          proj_g0w, proj_g0b, proj_g1w, proj_g1b, proj_g2w, proj_g2b,
          l2b + i * 128, w1h_i, w1l_i, w2h_i, w2l_i, mask);
    } else {
      epic_local_kernel<false><<<256, 1024, 0, stream>>>(
          xlf, pP_in, pP_out, cntp, cnt_g, context, xg_g, i,
          g1w_i, g1b_i, g2w_i, g2b_i, l1w_i, l1b_i,
          nullptr, nullptr, nullptr, nullptr, nullptr, nullptr,
          l2b + i * 128, w1h_i, w1l_i, w2h_i, w2l_i, mask);
    }
  }
  {
    const int i = NB_ - 1;  // layer 5
    epic_last_kernel<<<256, 512, 0, stream>>>(
        xlf, pPe1 /* written by layer 4 */, cnt_g, context, xg_g,
        g1w + (size_t)i * 128 * 282, g1b + i * 128,
        g2w + (size_t)i * 10 * 128, g2b + i * 10,
        l1w + (size_t)i * 128 * 154, l1b + i * 128,
        l2b + i * 128, w1h + i * 16384, w1l + i * 16384,
        w2h + i * 16384, w2l + i * 16384, mask, outw, outb, out);
  }
}

// Round 12
// 433.989 us; speedup vs baseline: 1.0484x; 1.0484x over previous
//
#include <hip/hip_runtime.h>
#include <hip/hip_bf16.h>

// EPiC network, round 23: r19 ordering restored + barrier-free dual-pass.
// r22 post-mortem: staging-after-tail EXPOSED the DMA drain (r19 hid it under
// the tail's barriers) -> reverted to stage-first. cnt-scalar shortcut kept
// (verified r22). New: wsum is WAVE-PRIVATE accumulated across passes A and B
// (r17-verified pattern) -> both mid-dispatch __syncthreads deleted; one
// barrier + one combine -> ONE pP slot per WG (pool NS 32->16, tail pool
// loads halve). De-convoys waves: frag-load bursts of different waves overlap
// other waves' K-loops. Only FP change: pool partial summation order.
// All GEMM/tail/prologue phase code verbatim r19/r22-verified.

typedef __attribute__((ext_vector_type(8))) short short8;
typedef __attribute__((ext_vector_type(4))) float f32x4;

#define B_ 16
#define N_ 8192
#define DC_ 16
#define H_ 128
#define G_ 10
#define NB_ 6
#define NEG_ 0.01f

__device__ __forceinline__ float lrelu(float x) { return x > 0.f ? x : NEG_ * x; }

__device__ __forceinline__ unsigned short f2bf(float x) {
  union { float f; unsigned u; } v; v.f = x;
  return (unsigned short)((v.u + 0x7fffu + ((v.u >> 16) & 1u)) >> 16);  // RNE
}
__device__ __forceinline__ float bf2f(unsigned short u) {
  union { unsigned u; float f; } v; v.u = ((unsigned)u) << 16; return v.f;
}
// truncating hi (1 op) + RNE lo of residual; pair represents x to ~2^-17
__device__ __forceinline__ void split_bf(float x, unsigned short& h, unsigned short& l) {
  union { float f; unsigned u; } v; v.f = x;
  unsigned hu = v.u & 0xffff0000u;
  h = (unsigned short)(hu >> 16);
  union { unsigned u; float f; } hv; hv.u = hu;
  l = f2bf(x - hv.f);
}

__device__ __forceinline__ f32x4 mfma16(short8 a, short8 b, f32x4 c) {
  return __builtin_amdgcn_mfma_f32_16x16x32_bf16(a, b, c, 0, 0, 0);
}

__device__ __forceinline__ void make_frags(f32x4 v0, f32x4 v1, short8& bh, short8& bl) {
  unsigned short h, l;
#pragma unroll
  for (int j = 0; j < 4; ++j) {
    split_bf(v0[j], h, l);
    bh[j] = (short)h; bl[j] = (short)l;
  }
#pragma unroll
  for (int j = 0; j < 4; ++j) {
    split_bf(v1[j], h, l);
    bh[4 + j] = (short)h; bl[4 + j] = (short)l;
  }
}

// async 16B-per-lane global -> LDS copy (lane-contiguous DMA)
__device__ __forceinline__ void async_cp16(const void* g, void* l) {
  __builtin_amdgcn_global_load_lds(
      (const __attribute__((address_space(1))) void*)g,
      (__attribute__((address_space(3))) void*)l, 16, 0, 0);
}

// agent-scope write-through publication (no L2 flush)
__device__ __forceinline__ void agent_store(float* p, float v) {
  __hip_atomic_store(p, v, __ATOMIC_RELAXED, __HIP_MEMORY_SCOPE_AGENT);
}
__device__ __forceinline__ float agent_load(const float* p) {
  return __hip_atomic_load(p, __ATOMIC_RELAXED, __HIP_MEMORY_SCOPE_AGENT);
}

// ---- common tail: pool(NS slots) -> h_g -> xg residual -> folded gbias ----
// blockDim-agnostic: compute guarded, barriers unconditional. (verified r19)
template <int NS>
__device__ void epic_global_tail(
    int b, int tid, const float* __restrict__ pP, float cnt,
    const float* __restrict__ xg_cur, float* __restrict__ xg_next,
    const float* __restrict__ context,
    const float* __restrict__ g1w_n, const float* __restrict__ g1b_n,
    const float* __restrict__ g2w_n, const float* __restrict__ g2b_n,
    const float* __restrict__ l1w_n, const float* __restrict__ l1b_n,
    float* __restrict__ gbias_out, float* shx) {
  if (tid < 256) {
    const int f = tid & 127, kh = tid >> 7;
    const float* pr = pP + ((size_t)b * NS + kh * (NS / 2)) * 128 + f;
    float s = 0.f;
#pragma unroll 8
    for (int w = 0; w < NS / 2; ++w) s += agent_load(pr + w * 128);
    shx[tid] = s;
  }
  __syncthreads();
  if (tid < 128) {
    float s = shx[tid] + shx[tid + 128];
    shx[384 + tid] = s;
    shx[256 + tid] = s / cnt;
  }
  if (tid < G_) shx[512 + tid] = xg_cur[tid];
  if (tid >= 32 && tid < 32 + DC_) shx[522 + tid - 32] = context[b * DC_ + tid - 32];
  __syncthreads();
  if (tid < 256) {
    const int f = tid & 127, kh = tid >> 7;
    const float* wr = g1w_n + (size_t)f * 282 + kh * 142;
    const float* vp = shx + 256 + kh * 142;
    const int n2 = kh ? 70 : 71;
    float a = 0.f;
#pragma unroll 8
    for (int j = 0; j < n2; ++j) {
      float2 w2 = *(const float2*)(wr + 2 * j);
      a += w2.x * vp[2 * j] + w2.y * vp[2 * j + 1];
    }
    shx[tid] = a;  // writes 0..255; reads were 256..539 (disjoint)
  }
  __syncthreads();
  if (tid < 128) shx[544 + tid] = lrelu(shx[tid] + shx[tid + 128] + g1b_n[tid]);
  __syncthreads();
  if (tid < G_) {
    const float* wr = g2w_n + tid * 128;
    float a = g2b_n[tid] + shx[512 + tid];
#pragma unroll 8
    for (int j = 0; j < 32; ++j) {
      float4 w4 = *(const float4*)(wr + 4 * j);
      a += w4.x * shx[544 + 4 * j] + w4.y * shx[544 + 4 * j + 1] +
           w4.z * shx[544 + 4 * j + 2] + w4.w * shx[544 + 4 * j + 3];
    }
    float v = lrelu(a);
    shx[672 + tid] = v;
    xg_next[tid] = v;
  }
  __syncthreads();
  if (tid < 128) {
    const float* wr = l1w_n + tid * 154;
    float a = l1b_n[tid];
#pragma unroll
    for (int j = 0; j < G_; ++j) a += wr[128 + j] * shx[672 + j];
#pragma unroll
    for (int j = 0; j < DC_; ++j) a += wr[138 + j] * shx[522 + j];
    gbias_out[tid] = a;
  }
  __syncthreads();
}

// ---- shared prologue: (FIRST: proj MLP -> xg_0) + this-layer tail ----
// cnt supplied by caller. gbias lands in LDS. (verified r19/r22 phase code)
template <bool FIRST, int NS>
__device__ void epic_prologue(
    int b, int tid, int layer, float cnt,
    const float* __restrict__ pP_in,
    const float* __restrict__ context, float* __restrict__ xg_g,
    const float* __restrict__ g1w_i, const float* __restrict__ g1b_i,
    const float* __restrict__ g2w_i, const float* __restrict__ g2b_i,
    const float* __restrict__ l1w_i, const float* __restrict__ l1b_i,
    const float* __restrict__ g0w, const float* __restrict__ g0b,
    const float* __restrict__ g1pw, const float* __restrict__ g1pb,
    const float* __restrict__ g2pw, const float* __restrict__ g2pb,
    float* gbias_s, float* shx) {
  if (FIRST) {
    // ---- proj global MLP: pool(128) -> g0 -> g1p -> g2p -> xg_0 ----
    if (tid < 256) {
      const int f = tid & 127, kh = tid >> 7;
      const float* pr = pP_in + ((size_t)b * 128 + kh * 64) * 128 + f;
      float s = 0.f;
#pragma unroll 8
      for (int w = 0; w < 64; ++w) s += agent_load(pr + w * 128);
      shx[tid] = s;
    }
    __syncthreads();
    if (tid < 128) {
      float s = shx[tid] + shx[tid + 128];
      shx[384 + tid] = s;
      shx[256 + tid] = s / cnt;
    }
    if (tid < DC_) shx[512 + tid] = context[b * DC_ + tid];
    __syncthreads();
    {
      float a = 0.f;
      if (tid < 256) {
        const int f = tid & 127, kh = tid >> 7;
        const float* wr = g0w + (size_t)f * 272 + kh * 136;
        const float* vp = shx + 256 + kh * 136;
#pragma unroll 8
        for (int j = 0; j < 34; ++j) {
          float4 w4 = *(const float4*)(wr + 4 * j);
          a += w4.x * vp[4 * j] + w4.y * vp[4 * j + 1] + w4.z * vp[4 * j + 2] + w4.w * vp[4 * j + 3];
        }
      }
      __syncthreads();
      if (tid < 256) shx[tid] = a;
    }
    __syncthreads();
    if (tid < 128) shx[544 + tid] = lrelu(shx[tid] + shx[tid + 128] + g0b[tid]);
    __syncthreads();
    {
      float a = 0.f;
      if (tid < 256) {
        const int f = tid & 127, kh = tid >> 7;
        const float* wr = g1pw + (size_t)f * 128 + kh * 64;
        const float* vp = shx + 544 + kh * 64;
#pragma unroll 8
        for (int j = 0; j < 16; ++j) {
          float4 w4 = *(const float4*)(wr + 4 * j);
          a += w4.x * vp[4 * j] + w4.y * vp[4 * j + 1] + w4.z * vp[4 * j + 2] + w4.w * vp[4 * j + 3];
        }
      }
      __syncthreads();
      if (tid < 256) shx[tid] = a;
    }
    __syncthreads();
    if (tid < 128) shx[544 + tid] = lrelu(shx[tid] + shx[tid + 128] + g1pb[tid]);
    __syncthreads();
    if (tid < G_) {
      const float* wr = g2pw + tid * 128;
      float a = g2pb[tid];
#pragma unroll 8
      for (int j = 0; j < 32; ++j) {
        float4 w4 = *(const float4*)(wr + 4 * j);
        a += w4.x * shx[544 + 4 * j] + w4.y * shx[544 + 4 * j + 1] +
             w4.z * shx[544 + 4 * j + 2] + w4.w * shx[544 + 4 * j + 3];
      }
      xg_g[(0 * 16 + b) * 16 + tid] = lrelu(a);  // identical across batch WGs
    }
    __syncthreads();
  }
  // ---- this layer's tail: gbias_i -> LDS, xg_{i+1} -> global slot ----
  epic_global_tail<NS>(b, tid, pP_in, cnt,
                       xg_g + ((size_t)layer * 16 + b) * 16,
                       xg_g + ((size_t)(layer + 1) * 16 + b) * 16, context,
                       g1w_i, g1b_i, g2w_i, g2b_i, l1w_i, l1b_i, gbias_s, shx);
}

// ---------------- weight prep: split + frag-order swizzle (3-term) ----------
__global__ __launch_bounds__(256) void prep_weights(
    const float* __restrict__ l1w, const float* __restrict__ l2w,
    unsigned short* __restrict__ w1h, unsigned short* __restrict__ w1l,
    unsigned short* __restrict__ w2h, unsigned short* __restrict__ w2l) {
  int idx = blockIdx.x * 256 + threadIdx.x;
  const int total = NB_ * H_ * H_;
  if (idx < total) {
    int i = idx / (H_ * H_), rem = idx % (H_ * H_);
    int F = rem / H_, k = rem % H_;
    int ks = k >> 5, c = k & 31;
    int mt2 = F >> 4, r2 = F & 15;
    int mt1 = ((F >> 5) << 1) | ((F >> 2) & 1);
    int r1 = (((F >> 3) & 3) << 2) | (F & 3);
    int off1 = i * 16384 + (mt1 * 4 + ks) * 512 + ((c >> 3) * 16 + r1) * 8 + (c & 7);
    int off2 = i * 16384 + (mt2 * 4 + ks) * 512 + ((c >> 3) * 16 + r2) * 8 + (c & 7);
    unsigned short h, l;
    split_bf(l1w[(i * H_ + F) * 154 + k], h, l);
    w1h[off1] = h; w1l[off1] = l;
    split_bf(l2w[(i * H_ + F) * H_ + k], h, l);
    w2h[off2] = h; w2l[off2] = l;
  }
}

// ---------------- projection local (pure local: xlf + pP + cntp) ----------
__global__ __launch_bounds__(256, 2) void proj_local_kernel(
    const float* __restrict__ xloc, const float* __restrict__ maskp,
    const float* __restrict__ plw, const float* __restrict__ plb,
    float* __restrict__ xlf, float* __restrict__ pP,
    float* __restrict__ cntp) {
  __shared__ float wq[H_][4];
  __shared__ float wsum[512];
  __shared__ float cw[4];
  const int tid = threadIdx.x, bid = blockIdx.x;
  const int wv = tid >> 6, lane = tid & 63;
  const int q = lane >> 4, n16 = lane & 15;
  if (tid < H_) {
    wq[tid][0] = plw[tid * 3 + 0];
    wq[tid][1] = plw[tid * 3 + 1];
    wq[tid][2] = plw[tid * 3 + 2];
    wq[tid][3] = plb[tid];
  }
  __syncthreads();
  const int t = bid * 4 + wv;            // 32-pt tile index
  const int p0 = t * 32;
  const int pa = p0 + n16, pb = p0 + 16 + n16;
  const float xa0 = xloc[pa * 3], xa1 = xloc[pa * 3 + 1], xa2 = xloc[pa * 3 + 2];
  const float xb0 = xloc[pb * 3], xb1 = xloc[pb * 3 + 1], xb2 = xloc[pb * 3 + 2];
  const float m0 = maskp[pa], m1 = maskp[pb];
  float* ga = xlf + (size_t)(2 * t) * 2048;
  float* gb = ga + 2048;
#pragma unroll
  for (int ms = 0; ms < 8; ++ms) {
    f32x4 v0, v1;
#pragma unroll
    for (int r = 0; r < 4; ++r) {
      const int F = ms * 16 + q * 4 + r;
      float4 w4 = *(const float4*)wq[F];
      v0[r] = lrelu(w4.x * xa0 + w4.y * xa1 + w4.z * xa2 + w4.w) * m0;
      v1[r] = lrelu(w4.x * xb0 + w4.y * xb1 + w4.z * xb2 + w4.w) * m1;
    }
    *(f32x4*)(ga + ms * 256 + (q * 16 + n16) * 4) = v0;
    *(f32x4*)(gb + ms * 256 + (q * 16 + n16) * 4) = v1;
    f32x4 s = v0 + v1;
#pragma unroll
    for (int r = 0; r < 4; ++r) {
      float sv = s[r];
      sv += __shfl_xor(sv, 1, 64);
      sv += __shfl_xor(sv, 2, 64);
      sv += __shfl_xor(sv, 4, 64);
      sv += __shfl_xor(sv, 8, 64);
      s[r] = sv;
    }
    if (n16 == 0) *(f32x4*)&wsum[wv * 128 + ms * 16 + q * 4] = s;
  }
  {
    float c = (q == 0) ? (m0 + m1) : 0.f;
    c += __shfl_xor(c, 1, 64);
    c += __shfl_xor(c, 2, 64);
    c += __shfl_xor(c, 4, 64);
    c += __shfl_xor(c, 8, 64);
    if (lane == 0) cw[wv] = c;
  }
  __syncthreads();
  // two 64-pt slots per WG -> 128 slots per batch
  if (tid < 128) {
    agent_store(&pP[(size_t)(2 * bid) * 128 + tid], wsum[tid] + wsum[128 + tid]);
    agent_store(&pP[(size_t)(2 * bid + 1) * 128 + tid], wsum[256 + tid] + wsum[384 + tid]);
  }
  if (tid == 0) agent_store(&cntp[bid], cw[0] + cw[1] + cw[2] + cw[3]);
}

// ---- per-group x B-frag load (B-layout, verified) ----
__device__ __forceinline__ void load_frags(const float* base_g, int q, int n16,
                                           short8* xbh, short8* xbl) {
#pragma unroll
  for (int ks = 0; ks < 4; ++ks) {
    const float* pb = base_g + (2 * ks + (q >> 1)) * 256 + ((q & 1) * 32 + n16) * 4;
    f32x4 v0 = *(const f32x4*)pb;
    f32x4 v1 = *(const f32x4*)(pb + 64);
    make_frags(v0, v1, xbh[ks], xbl[ks]);
  }
}

// ---- one group's K-loop + epilogue, 3-TERM; wsum row ACCUMULATES (r17) ----
template <bool LAST>
__device__ __forceinline__ void epic_pass(
    int g, int wv, int q, int n16, int lane16,
    const short8* xbh, const short8* xbl,
    const unsigned short* w1h_l, const unsigned short* w1l_l,
    const unsigned short* w2h_l, const unsigned short* w2l_l,
    const float* gbias_s, const float* l2b_s, const float* outw_s,
    float* wsum_row, float* __restrict__ xlf, const float* __restrict__ maskp,
    float* __restrict__ outp) {
  f32x4 acc2[8];
#pragma unroll
  for (int ms = 0; ms < 8; ++ms) acc2[ms] = (f32x4){0.f, 0.f, 0.f, 0.f};

#pragma unroll 1
  for (int ko = 0; ko < 4; ++ko) {
    f32x4 acc[2][2];
#pragma unroll
    for (int t = 0; t < 2; ++t)
#pragma unroll
      for (int kc = 0; kc < 2; ++kc) acc[t][kc] = (f32x4){0.f, 0.f, 0.f, 0.f};
#pragma unroll
    for (int t = 0; t < 2; ++t) {
#pragma unroll
      for (int kc = 0; kc < 2; ++kc) {  // ks chunks of 2 (16 transient regs)
        short8 a1h[2], a1l[2];
#pragma unroll
        for (int u = 0; u < 2; ++u) {
          const int off = ((ko * 2 + t) * 4 + kc * 2 + u) * 512 + lane16;
          a1h[u] = *(const short8*)(w1h_l + off);
          a1l[u] = *(const short8*)(w1l_l + off);
        }
#pragma unroll
        for (int u = 0; u < 2; ++u) {
          const int ks = kc * 2 + u;
          acc[t][kc] = mfma16(a1h[u], xbh[ks], acc[t][kc]);
          acc[t][kc] = mfma16(a1l[u], xbh[ks], acc[t][kc]);
          acc[t][kc] = mfma16(a1h[u], xbl[ks], acc[t][kc]);
        }
      }
    }
    f32x4 gb0 = *(const f32x4*)&gbias_s[ko * 32 + q * 8];
    f32x4 gb1 = *(const f32x4*)&gbias_s[ko * 32 + q * 8 + 4];
    f32x4 hv0, hv1;
#pragma unroll
    for (int r = 0; r < 4; ++r) {
      hv0[r] = lrelu(acc[0][0][r] + acc[0][1][r] + gb0[r]);
      hv1[r] = lrelu(acc[1][0][r] + acc[1][1][r] + gb1[r]);
    }
    short8 b2h, b2l;
    make_frags(hv0, hv1, b2h, b2l);
#pragma unroll
    for (int mc = 0; mc < 4; ++mc) {
      short8 a2h[2], a2l[2];
#pragma unroll
      for (int u = 0; u < 2; ++u) {
        const int off = ((mc * 2 + u) * 4 + ko) * 512 + lane16;
        a2h[u] = *(const short8*)(w2h_l + off);
        a2l[u] = *(const short8*)(w2l_l + off);
      }
#pragma unroll
      for (int u = 0; u < 2; ++u) {
        const int ms = mc * 2 + u;
        acc2[ms] = mfma16(a2h[u], b2h, acc2[ms]);
        acc2[ms] = mfma16(a2l[u], b2h, acc2[ms]);
        acc2[ms] = mfma16(a2h[u], b2l, acc2[ms]);
      }
    }
  }

  const float mk = maskp[g * 16 + n16];
  float po[3];
  if (LAST) po[0] = po[1] = po[2] = 0.f;
  float* base_w = xlf + (size_t)g * 2048;
#pragma unroll
  for (int ms = 0; ms < 8; ++ms) {
    f32x4 lb4 = *(const f32x4*)&l2b_s[ms * 16 + q * 4];
    float* xo = base_w + ms * 256 + (q * 16 + n16) * 4;
    f32x4 old = *(const f32x4*)xo;
    f32x4 v;
#pragma unroll
    for (int r = 0; r < 4; ++r) v[r] = lrelu(acc2[ms][r] + lb4[r] + old[r]) * mk;
    if (!LAST) {
      *(f32x4*)xo = v;
      f32x4 sr;
#pragma unroll
      for (int r = 0; r < 4; ++r) {
        float s = v[r];
        s += __shfl_xor(s, 1, 64);
        s += __shfl_xor(s, 2, 64);
        s += __shfl_xor(s, 4, 64);
        s += __shfl_xor(s, 8, 64);
        sr[r] = s;
      }
      if (n16 == 0) {
        f32x4 tcur = *(const f32x4*)&wsum_row[ms * 16 + q * 4];
        tcur += sr;
        *(f32x4*)&wsum_row[ms * 16 + q * 4] = tcur;  // wave-private RMW
      }
    } else {
      f32x4 w0 = *(const f32x4*)&outw_s[0 * 128 + ms * 16 + q * 4];
      f32x4 w1 = *(const f32x4*)&outw_s[1 * 128 + ms * 16 + q * 4];
      f32x4 w2 = *(const f32x4*)&outw_s[2 * 128 + ms * 16 + q * 4];
#pragma unroll
      for (int r = 0; r < 4; ++r) {
        po[0] += v[r] * w0[r];
        po[1] += v[r] * w1[r];
        po[2] += v[r] * w2[r];
      }
    }
  }
  if (LAST) {
#pragma unroll
    for (int o = 0; o < 3; ++o) {
      float s = po[o];
      s += __shfl_xor(s, 16, 64);
      s += __shfl_xor(s, 32, 64);
      po[o] = s;
    }
    if (q == 0) {
      const int p = g * 16 + n16;
#pragma unroll
      for (int o = 0; o < 3; ++o)
        outp[(size_t)p * 3 + o] = (po[o] + outw_s[384 + o]) * mk;
    }
  }
}

// -------- epic local (layers 0..4): stage -> tail -> barrier-free passes -----
template <bool FIRST>
__global__ __launch_bounds__(1024) void epic_local_kernel(
    float* __restrict__ xlf,
    const float* __restrict__ pP_in, float* __restrict__ pP_out,
    const float* __restrict__ cntp, float* __restrict__ cnt_g,
    const float* __restrict__ context,
    float* __restrict__ xg_g, int layer,
    const float* __restrict__ g1w_i, const float* __restrict__ g1b_i,
    const float* __restrict__ g2w_i, const float* __restrict__ g2b_i,
    const float* __restrict__ l1w_i, const float* __restrict__ l1b_i,
    const float* __restrict__ g0w, const float* __restrict__ g0b,
    const float* __restrict__ g1pw, const float* __restrict__ g1pb,
    const float* __restrict__ g2pw, const float* __restrict__ g2pb,
    const float* __restrict__ l2b,
    const unsigned short* __restrict__ w1h, const unsigned short* __restrict__ w1l,
    const unsigned short* __restrict__ w2h, const unsigned short* __restrict__ w2l,
    const float* __restrict__ maskp) {
  __shared__ unsigned short wbuf[65536];  // 128 KB: w1h|w1l|w2h|w2l
  __shared__ float shx[768];
  __shared__ float gbias_s[128];
  __shared__ float l2b_s[128];
  __shared__ float wsum[2048];
  const int tid = threadIdx.x, bid = blockIdx.x;
  const int b = bid >> 4;   // 16 WGs per batch
  const int wv = tid >> 6, lane = tid & 63;
  const int q = lane >> 4, n16 = lane & 15;

  // ---- stage weights FIRST (r19 order: DMA latency hides under tail) ----
  {
    const unsigned short* src =
        (wv < 4) ? w1h : (wv < 8) ? w1l : (wv < 12) ? w2h : w2l;
    const char* s8 = (const char*)(src + (wv & 3) * 4096) + lane * 16;
    char* d8 = (char*)wbuf + wv * 8192;  // wave-uniform dest (lane*16 implicit)
#pragma unroll
    for (int j = 0; j < 8; ++j) async_cp16(s8 + j * 1024, d8 + j * 1024);
  }
  if (tid < 128) l2b_s[tid] = l2b[tid];
  // zero wave-private wsum row (same-wave use only; no barrier needed)
  if (lane < 32) *(f32x4*)&wsum[wv * 128 + lane * 4] = (f32x4){0.f, 0.f, 0.f, 0.f};

  // ---- cnt: layer 0 computes + publishes; others load the scalar ----
  if (FIRST) {
    if (tid < 64) shx[688 + tid] = agent_load(&cntp[b * 64 + tid]);
    __syncthreads();
    if (tid == 0) {
      float c = 0.f;
#pragma unroll
      for (int w = 0; w < 64; ++w) c += shx[688 + w];
      shx[752] = c;
      agent_store(&cnt_g[b], c);
    }
    __syncthreads();
  } else {
    if (tid == 0) shx[752] = agent_load(&cnt_g[b]);
    __syncthreads();
  }
  const float cnt = shx[752];

  // ---- prologue: this layer's tail, all WGs, gbias -> LDS ----
  epic_prologue<FIRST, FIRST ? 128 : 16>(
      b, tid, layer, cnt, pP_in, context, xg_g,
      g1w_i, g1b_i, g2w_i, g2b_i, l1w_i, l1b_i,
      g0w, g0b, g1pw, g1pb, g2pw, g2pb, gbias_s, shx);

  // ---- group A frags loaded before the drain barrier (overlap with DMA) ----
  const int gA = bid * 32 + wv;
  const int gB = bid * 32 + 16 + wv;
  short8 xbh[4], xbl[4];
  load_frags(xlf + (size_t)gA * 2048, q, n16, xbh, xbl);
  __syncthreads();  // staging drained (vmcnt 0) + gbias ready

  const unsigned short* w1h_l = wbuf;
  const unsigned short* w1l_l = wbuf + 16384;
  const unsigned short* w2h_l = wbuf + 32768;
  const unsigned short* w2l_l = wbuf + 49152;
  const int lane16 = lane * 8;
  float* wrow = &wsum[wv * 128];

  // ---- pass A (no barriers: wsum row is wave-private) ----
  epic_pass<false>(gA, wv, q, n16, lane16, xbh, xbl, w1h_l, w1l_l, w2h_l, w2l_l,
                   gbias_s, l2b_s, nullptr, wrow, xlf, maskp, nullptr);
  // ---- pass B immediately (waves de-convoyed) ----
  load_frags(xlf + (size_t)gB * 2048, q, n16, xbh, xbl);
  epic_pass<false>(gB, wv, q, n16, lane16, xbh, xbl, w1h_l, w1l_l, w2h_l, w2l_l,
                   gbias_s, l2b_s, nullptr, wrow, xlf, maskp, nullptr);

  __syncthreads();
  if (tid < 128) {
    float s = 0.f;
#pragma unroll
    for (int w = 0; w < 16; ++w) s += wsum[w * 128 + tid];
    agent_store(&pP_out[(size_t)bid * 128 + tid], s);  // ONE slot per WG (NS=16)
  }
}

// -------------- LAST layer: stage -> tail -> head, 512 thr (r19 order) --------
__global__ __launch_bounds__(512, 2) void epic_last_kernel(
    const float* __restrict__ xlf,
    const float* __restrict__ pP_in, const float* __restrict__ cnt_g,
    const float* __restrict__ context, float* __restrict__ xg_g,
    const float* __restrict__ g1w_i, const float* __restrict__ g1b_i,
    const float* __restrict__ g2w_i, const float* __restrict__ g2b_i,
    const float* __restrict__ l1w_i, const float* __restrict__ l1b_i,
    const float* __restrict__ l2b,
    const unsigned short* __restrict__ w1h, const unsigned short* __restrict__ w1l,
    const unsigned short* __restrict__ w2h, const unsigned short* __restrict__ w2l,
    const float* __restrict__ maskp,
    const float* __restrict__ outw, const float* __restrict__ outb,
    float* __restrict__ outp) {
  __shared__ unsigned short wbuf[65536];  // 128 KB
  __shared__ float shx[768];
  __shared__ float gbias_s[128];
  __shared__ float l2b_s[128];
  __shared__ float outw_s[392];
  const int tid = threadIdx.x, bid = blockIdx.x;
  const int b = bid >> 4;
  const int wv = tid >> 6, lane = tid & 63;
  const int q = lane >> 4, n16 = lane & 15;
  const int lane16 = lane * 8;

  {
    const unsigned short* src =
        (wv < 2) ? w1h : (wv < 4) ? w1l : (wv < 6) ? w2h : w2l;
    const char* s8 = (const char*)(src + (wv & 1) * 8192) + lane * 16;
    char* d8 = (char*)wbuf + wv * 16384;
#pragma unroll
    for (int j = 0; j < 16; ++j) async_cp16(s8 + j * 1024, d8 + j * 1024);
  }
  if (tid < 128) l2b_s[tid] = l2b[tid];
  if (tid < 384) outw_s[tid] = outw[tid];
  if (tid >= 384 && tid < 387) outw_s[tid] = outb[tid - 384];

  // ---- cnt from published scalar ----
  if (tid == 0) shx[752] = agent_load(&cnt_g[b]);
  __syncthreads();
  const float cnt = shx[752];

  // ---- prologue: layer-5 tail (gbias_5 -> LDS); staging drains under it ----
  epic_prologue<false, 16>(
      b, tid, 5, cnt, pP_in, context, xg_g,
      g1w_i, g1b_i, g2w_i, g2b_i, l1w_i, l1b_i,
      nullptr, nullptr, nullptr, nullptr, nullptr, nullptr, gbias_s, shx);
  __syncthreads();  // gbias_s ready; staging drained

  const unsigned short* w1h_l = wbuf;
  const unsigned short* w1l_l = wbuf + 16384;
  const unsigned short* w2h_l = wbuf + 32768;
  const unsigned short* w2l_l = wbuf + 49152;

#pragma unroll 1
  for (int p4 = 0; p4 < 4; ++p4) {
    const int g = bid * 32 + wv * 4 + p4;
    short8 xbh[4], xbl[4];
    load_frags(xlf + (size_t)g * 2048, q, n16, xbh, xbl);
    epic_pass<true>(g, wv, q, n16, lane16, xbh, xbl, w1h_l, w1l_l, w2h_l, w2l_l,
                    gbias_s, l2b_s, outw_s, gbias_s /*dead*/,
                    const_cast<float*>(xlf), maskp, outp);
  }
}

extern "C" void kernel_launch(void* const* d_in, const int* in_sizes, int n_in,
                              void* d_out, int out_size, void* d_ws, size_t ws_size,
                              hipStream_t stream) {
  const float* x_local = (const float*)d_in[0];
  const float* context = (const float*)d_in[1];
  const float* mask = (const float*)d_in[2];
  const float* proj_lw = (const float*)d_in[3];
  const float* proj_lb = (const float*)d_in[4];
  const float* proj_g0w = (const float*)d_in[5];
  const float* proj_g0b = (const float*)d_in[6];
  const float* proj_g1w = (const float*)d_in[7];
  const float* proj_g1b = (const float*)d_in[8];
  const float* proj_g2w = (const float*)d_in[9];
  const float* proj_g2b = (const float*)d_in[10];
  const float* g1w = (const float*)d_in[11];
  const float* g1b = (const float*)d_in[12];
  const float* g2w = (const float*)d_in[13];
  const float* g2b = (const float*)d_in[14];
  const float* l1w = (const float*)d_in[15];
  const float* l1b = (const float*)d_in[16];
  const float* l2w = (const float*)d_in[17];
  const float* l2b = (const float*)d_in[18];
  const float* outw = (const float*)d_in[19];
  const float* outb = (const float*)d_in[20];
  float* out = (float*)d_out;

  char* ws = (char*)d_ws;
  float* xlf = (float*)ws;                                  // 67,108,864
  float* pP = (float*)(ws + 67108864);                      //  1,048,576 (proj, 128 slots/batch)
  float* cntp = (float*)(ws + 68157440);                    //      4,096
  float* cnt_g = (float*)(ws + 68161536);                   //         64
  float* xg_g = (float*)(ws + 68161600);                    //      7,168 (7 slots x 16 batches x 16)
  unsigned short* w1h = (unsigned short*)(ws + 68218368);   //    196,608
  unsigned short* w1l = (unsigned short*)(ws + 68414976);   //    196,608
  unsigned short* w2h = (unsigned short*)(ws + 68611584);   //    196,608
  unsigned short* w2l = (unsigned short*)(ws + 68808192);   //    196,608
  float* pPe0 = (float*)(ws + 69004800);                    //    131,072 used (epic pool ping)
  float* pPe1 = (float*)(ws + 69266944);                    //    131,072 used (epic pool pong)
  // end: 69,529,088 (< proven 70,018,304)

  prep_weights<<<384, 256, 0, stream>>>(l1w, l2w, w1h, w1l, w2h, w2l);
  proj_local_kernel<<<1024, 256, 0, stream>>>(
      x_local, mask, proj_lw, proj_lb, xlf, pP, cntp);
  for (int i = 0; i < NB_ - 1; ++i) {  // layers 0..4
    const float* pP_in = (i == 0) ? pP : ((i & 1) ? pPe1 : pPe0);
    float* pP_out = ((i + 1) & 1) ? pPe1 : pPe0;
    const float* g1w_i = g1w + (size_t)i * 128 * 282;
    const float* g1b_i = g1b + i * 128;
    const float* g2w_i = g2w + (size_t)i * 10 * 128;
    const float* g2b_i = g2b + i * 10;
    const float* l1w_i = l1w + (size_t)i * 128 * 154;
    const float* l1b_i = l1b + i * 128;
    const unsigned short* w1h_i = w1h + i * 16384;
    const unsigned short* w1l_i = w1l + i * 16384;
    const unsigned short* w2h_i = w2h + i * 16384;
    const unsigned short* w2l_i = w2l + i * 16384;
    if (i == 0) {
      epic_local_kernel<true><<<256, 1024, 0, stream>>>(
          xlf, pP_in, pP_out, cntp, cnt_g, context, xg_g, i,
          g1w_i, g1b_i, g2w_i, g2b_i, l1w_i, l1b_i,
          proj_g0w, proj_g0b, proj_g1w, proj_g1b, proj_g2w, proj_g2b,
          l2b + i * 128, w1h_i, w1l_i, w2h_i, w2l_i, mask);
    } else {
      epic_local_kernel<false><<<256, 1024, 0, stream>>>(
          xlf, pP_in, pP_out, cntp, cnt_g, context, xg_g, i,
          g1w_i, g1b_i, g2w_i, g2b_i, l1w_i, l1b_i,
          nullptr, nullptr, nullptr, nullptr, nullptr, nullptr,
          l2b + i * 128, w1h_i, w1l_i, w2h_i, w2l_i, mask);
    }
  }
  {
    const int i = NB_ - 1;  // layer 5
    epic_last_kernel<<<256, 512, 0, stream>>>(
        xlf, pPe1 /* written by layer 4 */, cnt_g, context, xg_g,
        g1w + (size_t)i * 128 * 282, g1b + i * 128,
        g2w + (size_t)i * 10 * 128, g2b + i * 10,
        l1w + (size_t)i * 128 * 154, l1b + i * 128,
        l2b + i * 128, w1h + i * 16384, w1l + i * 16384,
        w2h + i * 16384, w2l + i * 16384, mask, outw, outb, out);
  }
}